// Round 4
// baseline (5859.024 us; speedup 1.0000x reference)
//
#include <hip/hip_runtime.h>
#include <stdint.h>

#define N_NODESC 65536
#define N_EDGESC 1048576
#define HIDC 128
#define NUM_GRAPHSC 512
#define NUM_CLASSESC 10
#define NUM_EXPERTSC 4
#define NUM_LAYERSC 3

// ---------------- threefry2x32 (JAX-compatible, 20 rounds) ----------------
__host__ __device__ __forceinline__ uint32_t rotl32(uint32_t v, int r) {
  return (v << r) | (v >> (32 - r));
}
__host__ __device__ inline void threefry2x32(uint32_t k0, uint32_t k1,
                                             uint32_t x0, uint32_t x1,
                                             uint32_t* o0, uint32_t* o1) {
  uint32_t k2 = k0 ^ k1 ^ 0x1BD11BDAu;
  x0 += k0; x1 += k1;
#define TF_R(r) x0 += x1; x1 = rotl32(x1, r); x1 ^= x0;
  TF_R(13) TF_R(15) TF_R(26) TF_R(6)
  x0 += k1; x1 += k2 + 1u;
  TF_R(17) TF_R(29) TF_R(16) TF_R(24)
  x0 += k2; x1 += k0 + 2u;
  TF_R(13) TF_R(15) TF_R(26) TF_R(6)
  x0 += k0; x1 += k1 + 3u;
  TF_R(17) TF_R(29) TF_R(16) TF_R(24)
  x0 += k1; x1 += k2 + 4u;
  TF_R(13) TF_R(15) TF_R(26) TF_R(6)
  x0 += k2; x1 += k0 + 5u;
#undef TF_R
  *o0 = x0; *o1 = x1;
}

// exact f32 uniform value as JAX computes it (f32 path, bits>>9 mantissa fill)
__device__ __forceinline__ float uniform_from_bits(uint32_t b) {
  float f = __uint_as_float((b >> 9) | 0x3f800000u) - 1.0f;  // [0,1), exact
  const float mn = 1e-6f;
  const float mx = 1.0f - 1e-6f;
  return fmaxf(mn, __fadd_rn(__fmul_rn(f, __fsub_rn(mx, mn)), mn));
}

// ---------------- CSR build ----------------
__global__ void khist(const int* __restrict__ dst, int* __restrict__ deg) {
  int e = blockIdx.x * 256 + threadIdx.x;
  if (e < N_EDGESC) atomicAdd(&deg[dst[e]], 1);
}

__global__ void kscan(const int* __restrict__ deg, int* __restrict__ offs) {
  __shared__ int part[1024];
  int t = threadIdx.x;
  int base = t * 64;
  int s = 0;
  for (int i = 0; i < 64; ++i) s += deg[base + i];
  part[t] = s;
  __syncthreads();
  for (int off = 1; off < 1024; off <<= 1) {
    int v = 0;
    if (t >= off) v = part[t - off];
    __syncthreads();
    part[t] += v;
    __syncthreads();
  }
  int run = part[t] - s;  // exclusive prefix
  for (int i = 0; i < 64; ++i) {
    int d = deg[base + i];
    offs[base + i] = run;
    run += d;
  }
  if (t == 1023) offs[N_NODESC] = run;
}

__global__ void kfill(const int* __restrict__ src, const int* __restrict__ dst,
                      int* __restrict__ curs, int* __restrict__ csr_src,
                      int* __restrict__ csr_eid) {
  int e = blockIdx.x * 256 + threadIdx.x;
  if (e >= N_EDGESC) return;
  int d = dst[e];
  int p = atomicAdd(&curs[d], 1);
  csr_src[p] = src[e];
  csr_eid[p] = e;
}

// sort each node's edge list by eid: accumulation order == np.add.at (e ascending)
__global__ void ksort(const int* __restrict__ offs, int* __restrict__ csr_src,
                      int* __restrict__ csr_eid) {
  int n = blockIdx.x * 256 + threadIdx.x;
  if (n >= N_NODESC) return;
  int s = offs[n], e = offs[n + 1];
  for (int i = s + 1; i < e; ++i) {
    int ke = csr_eid[i], ks = csr_src[i];
    int j = i - 1;
    while (j >= s && csr_eid[j] > ke) {
      csr_eid[j + 1] = csr_eid[j];
      csr_src[j + 1] = csr_src[j];
      --j;
    }
    csr_eid[j + 1] = ke;
    csr_src[j + 1] = ks;
  }
}

__global__ void kbounds(const int* __restrict__ batch, int* __restrict__ bounds) {
  int g = threadIdx.x;  // 512 threads, 1 block
  int lo = 0, hi = N_NODESC;
  while (lo < hi) {
    int mid = (lo + hi) >> 1;
    if (batch[mid] < g) lo = mid + 1; else hi = mid;
  }
  bounds[g] = lo;
  if (g == 0) bounds[NUM_GRAPHSC] = N_NODESC;
}

// ---------------- GIN aggregate + combine: z = (1+eps)*h + segsum(h[src]) ----
__global__ void gather_z(const float* __restrict__ hin,
                         const int* __restrict__ offs,
                         const int* __restrict__ csr_src,
                         const int* __restrict__ csr_eid,
                         const float* __restrict__ ew,   // nullable, index eid*4
                         const float* __restrict__ epsArr, int l,
                         float* __restrict__ zout) {
  int gt = blockIdx.x * blockDim.x + threadIdx.x;
  int n = gt >> 6;
  int lane = gt & 63;
  if (n >= N_NODESC) return;
  int s = offs[n], e = offs[n + 1];
  float ax = 0.f, ay = 0.f;
  if (ew) {
    for (int i = s; i < e; ++i) {
      int sn = csr_src[i];
      float w = ew[(size_t)csr_eid[i] * 4];
      const float2 v = *(const float2*)&hin[(size_t)sn * HIDC + lane * 2];
      ax = __fadd_rn(ax, __fmul_rn(v.x, w));
      ay = __fadd_rn(ay, __fmul_rn(v.y, w));
    }
  } else {
    for (int i = s; i < e; ++i) {
      int sn = csr_src[i];
      const float2 v = *(const float2*)&hin[(size_t)sn * HIDC + lane * 2];
      ax = __fadd_rn(ax, v.x);
      ay = __fadd_rn(ay, v.y);
    }
  }
  float ep = __fadd_rn(1.0f, epsArr[l]);
  const float2 hv = *(const float2*)&hin[(size_t)n * HIDC + lane * 2];
  ax = __fadd_rn(__fmul_rn(ep, hv.x), ax);
  ay = __fadd_rn(__fmul_rn(ep, hv.y), ay);
  float2 o; o.x = ax; o.y = ay;
  *(float2*)&zout[(size_t)n * HIDC + lane * 2] = o;
}

// ---- fp32 GEMM: C[M,128] = act(X[M,128] @ W[128,128] + b) ----
// Per-element K-chain: sequential ascending k, single accumulator, FMA —
// matches an OpenBLAS FMA sgemm microkernel's per-element order (KC>=128).
__global__ __launch_bounds__(256, 1)
void gemm128(const float* __restrict__ X, const float* __restrict__ W,
             const float* __restrict__ bias, float* __restrict__ outp,
             int doRelu) {
  __shared__ float sX[HIDC][HIDC];  // transposed: sX[k][m]
  __shared__ float sW[HIDC][HIDC];  // sW[k][n]
  const int tid = threadIdx.x;
  const size_t base = (size_t)blockIdx.x * HIDC * HIDC;

  const float4* Wv = (const float4*)W;
  float4* sWv = (float4*)(&sW[0][0]);
#pragma unroll
  for (int i = 0; i < 16; ++i) sWv[tid + 256 * i] = Wv[tid + 256 * i];

  const float4* Xv = (const float4*)(X + base);
#pragma unroll
  for (int i = 0; i < 16; ++i) {
    int idx = tid + 256 * i;
    float4 v = Xv[idx];
    int m = idx >> 5;
    int kq = (idx & 31) << 2;
    sX[kq + 0][m] = v.x; sX[kq + 1][m] = v.y;
    sX[kq + 2][m] = v.z; sX[kq + 3][m] = v.w;
  }
  __syncthreads();

  const int tm = (tid >> 4) << 3;
  const int tn = (tid & 15) << 3;
  float acc[8][8];
#pragma unroll
  for (int i = 0; i < 8; ++i)
#pragma unroll
    for (int j = 0; j < 8; ++j) acc[i][j] = 0.0f;

#pragma unroll 4
  for (int k = 0; k < HIDC; ++k) {
    float a[8], b[8];
    *(float4*)&a[0] = *(const float4*)&sX[k][tm];
    *(float4*)&a[4] = *(const float4*)&sX[k][tm + 4];
    *(float4*)&b[0] = *(const float4*)&sW[k][tn];
    *(float4*)&b[4] = *(const float4*)&sW[k][tn + 4];
#pragma unroll
    for (int i = 0; i < 8; ++i)
#pragma unroll
      for (int j = 0; j < 8; ++j) acc[i][j] = fmaf(a[i], b[j], acc[i][j]);
  }

  float bvals[8];
#pragma unroll
  for (int j = 0; j < 8; ++j) bvals[j] = bias ? bias[tn + j] : 0.0f;
#pragma unroll
  for (int i = 0; i < 8; ++i) {
    float r[8];
#pragma unroll
    for (int j = 0; j < 8; ++j) {
      float v = __fadd_rn(acc[i][j], bvals[j]);
      if (doRelu) v = fmaxf(v, 0.0f);
      r[j] = v;
    }
    float* orow = outp + base + (size_t)(tm + i) * HIDC + tn;
    *(float4*)&orow[0] = *(float4*)&r[0];
    *(float4*)&orow[4] = *(float4*)&r[4];
  }
}

// ---------------- r[n] = dot(X[n,:], w) + b ----------------
__global__ void rowdot(const float* __restrict__ X, const float* __restrict__ w,
                       const float* __restrict__ bptr, float* __restrict__ r) {
  int gt = blockIdx.x * blockDim.x + threadIdx.x;
  int row = gt >> 6, lane = gt & 63;
  if (row >= N_NODESC) return;
  const float2 x = *(const float2*)&X[(size_t)row * HIDC + lane * 2];
  const float2 ww = *(const float2*)&w[lane * 2];
  float p = x.x * ww.x + x.y * ww.y;
#pragma unroll
  for (int m = 32; m; m >>= 1) p += __shfl_xor(p, m, 64);
  if (lane == 0) r[row] = p + bptr[0];
}

// ---------------- edge logit: relu(A[src]+B[dst]+b1) . w2 + b2 --------------
__global__ void edge_logit(const float* __restrict__ A, const float* __restrict__ Bm,
                           const int* __restrict__ src, const int* __restrict__ dst,
                           const float* __restrict__ b1, const float* __restrict__ w2,
                           const float* __restrict__ b2, float* __restrict__ el) {
  int gt = blockIdx.x * blockDim.x + threadIdx.x;
  int e = gt >> 6, lane = gt & 63;
  if (e >= N_EDGESC) return;
  int s = src[e], d = dst[e];
  const float2 a = *(const float2*)&A[(size_t)s * HIDC + lane * 2];
  const float2 b = *(const float2*)&Bm[(size_t)d * HIDC + lane * 2];
  const float2 bb = *(const float2*)&b1[lane * 2];
  const float2 w = *(const float2*)&w2[lane * 2];
  float h0 = fmaxf(__fadd_rn(__fadd_rn(a.x, b.x), bb.x), 0.0f);
  float h1 = fmaxf(__fadd_rn(__fadd_rn(a.y, b.y), bb.y), 0.0f);
  float p = h0 * w.x + h1 * w.y;
#pragma unroll
  for (int m = 32; m; m >>= 1) p += __shfl_xor(p, m, 64);
  if (lane == 0) el[e] = p + b2[0];
}

// ---------------- hard-concrete sampling, f32-faithful decision -------------
// Fast path: device logf, sign(marg), valid when |marg| > GATE (errors ~2e-6).
// Borderline: correctly-rounded f32 stages via f64, then the exact f32
// sigmoid expression 1/(1+exp(-(l+g)/0.1f)) > 0.5f (reproduces the ~6e-9
// dead zone above 0 that a sign test misses).
__global__ void ksample(const float* __restrict__ lg, int n, uint32_t key0,
                        uint32_t key1, float* __restrict__ outp, int featMode) {
  int i = blockIdx.x * 256 + threadIdx.x;
  if (i >= n) return;
  uint32_t o0, o1;
  threefry2x32(key0, key1, 0u, (uint32_t)i, &o0, &o1);
  float u = uniform_from_bits(o0 ^ o1);
  float l = lg[i];
  // fast approximate gumbel
  float tf = -__logf(u);
  float gf = -__logf(tf);
  float margf = l + gf;
  float m;
  if (fabsf(margf) > 1e-4f) {
    m = (margf > 0.0f) ? 1.0f : 0.0f;
  } else {
    // correctly-rounded f32 stage replay
    float t32 = (float)(-log((double)u));           // f32(log u), CR
    float g32 = (float)(-log((double)t32));         // f32(log t), CR
    float m32 = __fadd_rn(l, g32);                  // l + g in f32
    float q = m32 / 0.1f;                           // f32 division (IEEE)
    float e32 = (float)exp(-(double)q);             // f32(exp(-q)), CR
    float den = __fadd_rn(1.0f, e32);
    float s = 1.0f / den;
    m = (s > 0.5f) ? 1.0f : 0.0f;
  }
  if (featMode)
    outp[(size_t)(i >> 7) * (NUM_EXPERTSC * HIDC) + (i & 127)] = m;
  else
    outp[(size_t)i * NUM_EXPERTSC] = m;
}

// ---------------- masked_x = x * node_mask * feat_mask ----------------
__global__ void kmaskx(const float* __restrict__ x, const float* __restrict__ nmask,
                       const float* __restrict__ fmask, float* __restrict__ outp) {
  int idx = blockIdx.x * 256 + threadIdx.x;  // quad index
  int n = idx >> 5;
  if (n >= N_NODESC) return;
  int q = (idx & 31) << 2;
  float nm = nmask[(size_t)n * NUM_EXPERTSC];
  float4 xv = *(const float4*)&x[(size_t)n * HIDC + q];
  float4 fv = *(const float4*)&fmask[(size_t)n * (NUM_EXPERTSC * HIDC) + q];
  float4 o;
  o.x = xv.x * nm * fv.x; o.y = xv.y * nm * fv.y;
  o.z = xv.z * nm * fv.z; o.w = xv.w * nm * fv.w;
  *(float4*)&outp[(size_t)n * HIDC + q] = o;
}

// ---------------- mean pool by graph ----------------
__global__ void pool(const float* __restrict__ h, const int* __restrict__ bounds,
                     float* __restrict__ outp, int rowStride) {
  int g = blockIdx.x, j = threadIdx.x;
  int s = bounds[g], e = bounds[g + 1];
  float acc = 0.0f;
  for (int i = s; i < e; ++i) acc = __fadd_rn(acc, h[(size_t)i * HIDC + j]);
  int cnt = e - s; if (cnt < 1) cnt = 1;
  outp[(size_t)g * rowStride + j] = acc / (float)cnt;
}

// ---------------- classifier ----------------
__global__ void kcls(const float* __restrict__ hst, const float* __restrict__ w,
                     const float* __restrict__ b, float* __restrict__ outp) {
  int g = blockIdx.x, c = threadIdx.x;
  if (c >= NUM_CLASSESC) return;
  float acc = 0.0f;
  for (int j = 0; j < HIDC; ++j)
    acc = __fadd_rn(acc, __fmul_rn(hst[(size_t)g * (NUM_EXPERTSC * HIDC) + j],
                                   w[j * NUM_CLASSESC + c]));
  outp[(size_t)g * (NUM_EXPERTSC * NUM_CLASSESC) + c] = acc + b[c];
}

// ---------------- launch ----------------
extern "C" void kernel_launch(void* const* d_in, const int* in_sizes, int n_in,
                              void* d_out, int out_size, void* d_ws, size_t ws_size,
                              hipStream_t stream) {
  const float* x    = (const float*)d_in[0];
  const int* eidx   = (const int*)d_in[1];
  const int* batch  = (const int*)d_in[2];
  const float* cw1  = (const float*)d_in[3];
  const float* cb1  = (const float*)d_in[4];
  const float* cw2  = (const float*)d_in[5];
  const float* cb2  = (const float*)d_in[6];
  const float* ceps = (const float*)d_in[7];
  const float* kw1  = (const float*)d_in[8];
  const float* kb1  = (const float*)d_in[9];
  const float* kw2  = (const float*)d_in[10];
  const float* kb2  = (const float*)d_in[11];
  const float* keps = (const float*)d_in[12];
  const float* nm_w1 = (const float*)d_in[13];
  const float* nm_b1 = (const float*)d_in[14];
  const float* nm_w2 = (const float*)d_in[15];
  const float* nm_b2 = (const float*)d_in[16];
  const float* em_w1 = (const float*)d_in[17];
  const float* em_b1 = (const float*)d_in[18];
  const float* em_w2 = (const float*)d_in[19];
  const float* em_b2 = (const float*)d_in[20];
  const float* fm_w1 = (const float*)d_in[21];
  const float* fm_b1 = (const float*)d_in[22];
  const float* fm_w2 = (const float*)d_in[23];
  const float* fm_b2 = (const float*)d_in[24];
  const float* cls_w = (const float*)d_in[25];
  const float* cls_b = (const float*)d_in[26];

  const int* src = eidx;
  const int* dstp = eidx + N_EDGESC;
  float* out = (float*)d_out;

  // output layout (floats)
  const size_t OFF_HST    = 20480;
  const size_t OFF_HORIG  = 282624;
  const size_t OFF_NODE   = 348160;
  const size_t OFF_EDGE   = 610304;
  const size_t OFF_FEAT   = 4804608;

  // workspace layout
  const size_t NH = (size_t)N_NODESC * HIDC;
  float* Z    = (float*)d_ws;
  float* hb   = Z + NH;
  float* tmp  = hb + NH;
  float* agg  = tmp + NH;
  float* el   = agg + NH;
  float* nl   = el + N_EDGESC;
  int* deg    = (int*)(nl + N_NODESC);
  int* offs   = deg + N_NODESC;
  int* curs   = offs + N_NODESC + 1;
  int* csr_s  = curs + N_NODESC;
  int* csr_e  = csr_s + N_EDGESC;
  int* bounds = csr_e + N_EDGESC;

  // host-side key derivation (JAX threefry, partitionable-mode split)
  uint32_t kk[NUM_EXPERTSC][3][2];
  for (int k = 0; k < NUM_EXPERTSC; ++k) {
    uint32_t f0, f1;
    threefry2x32(0u, 42u, 0u, (uint32_t)k, &f0, &f1);
    threefry2x32(f0, f1, 0u, 0u, &kk[k][0][0], &kk[k][0][1]);
    threefry2x32(f0, f1, 0u, 1u, &kk[k][1][0], &kk[k][1][1]);
    threefry2x32(f0, f1, 0u, 2u, &kk[k][2][0], &kk[k][2][1]);
  }

  // ---- CSR build ----
  hipMemsetAsync(deg, 0, N_NODESC * sizeof(int), stream);
  khist<<<N_EDGESC / 256, 256, 0, stream>>>(dstp, deg);
  kscan<<<1, 1024, 0, stream>>>(deg, offs);
  hipMemcpyAsync(curs, offs, N_NODESC * sizeof(int), hipMemcpyDeviceToDevice, stream);
  kfill<<<N_EDGESC / 256, 256, 0, stream>>>(src, dstp, curs, csr_s, csr_e);
  ksort<<<N_NODESC / 256, 256, 0, stream>>>(offs, csr_s, csr_e);
  kbounds<<<1, NUM_GRAPHSC, 0, stream>>>(batch, bounds);

  const int GZ_GRID = N_NODESC * 64 / 256;   // 16384
  const int GEMM_GRID = N_NODESC / HIDC;     // 512

  // ---- clean encoder (f32 faithful) -> Z ----
  for (int l = 0; l < NUM_LAYERSC; ++l) {
    const float* hin = (l == 0) ? x : hb;
    gather_z<<<GZ_GRID, 256, 0, stream>>>(hin, offs, csr_s, csr_e, nullptr, ceps, l, agg);
    gemm128<<<GEMM_GRID, 256, 0, stream>>>(agg, cw1 + (size_t)l * HIDC * HIDC,
                                           cb1 + l * HIDC, tmp, 1);
    gemm128<<<GEMM_GRID, 256, 0, stream>>>(tmp, cw2 + (size_t)l * HIDC * HIDC,
                                           cb2 + l * HIDC,
                                           (l == NUM_LAYERSC - 1) ? Z : hb,
                                           (l < NUM_LAYERSC - 1) ? 1 : 0);
  }
  pool<<<NUM_GRAPHSC, HIDC, 0, stream>>>(Z, bounds, out + OFF_HORIG, HIDC);

  // ---- experts ----
  for (int k = 0; k < NUM_EXPERTSC; ++k) {
    // node mask
    gemm128<<<GEMM_GRID, 256, 0, stream>>>(Z, nm_w1 + (size_t)k * HIDC * HIDC,
                                           nm_b1 + k * HIDC, tmp, 1);
    rowdot<<<GZ_GRID, 256, 0, stream>>>(tmp, nm_w2 + (size_t)k * HIDC, nm_b2 + k, nl);
    ksample<<<N_NODESC / 256, 256, 0, stream>>>(nl, N_NODESC, kk[k][0][0], kk[k][0][1],
                                                out + OFF_NODE + k, 0);
    // feature mask (both layers via the faithful sequential-K GEMM)
    gemm128<<<GEMM_GRID, 256, 0, stream>>>(Z, fm_w1 + (size_t)k * HIDC * HIDC,
                                           fm_b1 + k * HIDC, tmp, 1);
    gemm128<<<GEMM_GRID, 256, 0, stream>>>(tmp, fm_w2 + (size_t)k * HIDC * HIDC,
                                           fm_b2 + (size_t)k * HIDC, agg, 0);
    ksample<<<(N_NODESC * HIDC) / 256, 256, 0, stream>>>(agg, N_NODESC * HIDC,
                                                         kk[k][2][0], kk[k][2][1],
                                                         out + OFF_FEAT + (size_t)k * HIDC, 1);
    // edge mask: factor concat-GEMM into A(src)+B(dst); b1 folded in edge_logit
    gemm128<<<GEMM_GRID, 256, 0, stream>>>(Z, em_w1 + (size_t)k * 2 * HIDC * HIDC,
                                           nullptr, tmp, 0);
    gemm128<<<GEMM_GRID, 256, 0, stream>>>(Z, em_w1 + (size_t)k * 2 * HIDC * HIDC + HIDC * HIDC,
                                           nullptr, agg, 0);
    edge_logit<<<N_EDGESC * 64 / 256, 256, 0, stream>>>(tmp, agg, src, dstp,
                                                        em_b1 + k * HIDC,
                                                        em_w2 + (size_t)k * HIDC,
                                                        em_b2 + k, el);
    ksample<<<N_EDGESC / 256, 256, 0, stream>>>(el, N_EDGESC, kk[k][1][0], kk[k][1][1],
                                                out + OFF_EDGE + k, 0);
    // masked encoder
    kmaskx<<<N_NODESC * 32 / 256, 256, 0, stream>>>(x, out + OFF_NODE + k,
                                                    out + OFF_FEAT + (size_t)k * HIDC, hb);
    for (int l = 0; l < NUM_LAYERSC; ++l) {
      gather_z<<<GZ_GRID, 256, 0, stream>>>(hb, offs, csr_s, csr_e,
                                            out + OFF_EDGE + k, keps, l, agg);
      gemm128<<<GEMM_GRID, 256, 0, stream>>>(agg, kw1 + (size_t)l * HIDC * HIDC,
                                             kb1 + l * HIDC, tmp, 1);
      gemm128<<<GEMM_GRID, 256, 0, stream>>>(tmp, kw2 + (size_t)l * HIDC * HIDC,
                                             kb2 + l * HIDC, hb,
                                             (l < NUM_LAYERSC - 1) ? 1 : 0);
    }
    pool<<<NUM_GRAPHSC, HIDC, 0, stream>>>(hb, bounds, out + OFF_HST + k * HIDC,
                                           NUM_EXPERTSC * HIDC);
    kcls<<<NUM_GRAPHSC, 64, 0, stream>>>(out + OFF_HST + k * HIDC,
                                         cls_w + (size_t)k * HIDC * NUM_CLASSESC,
                                         cls_b + k * NUM_CLASSESC,
                                         out + k * NUM_CLASSESC);
  }
}

// Round 6
// 4321.449 us; speedup vs baseline: 1.3558x; 1.3558x over previous
//
#include <hip/hip_runtime.h>
#include <stdint.h>

#define N_NODESC 65536
#define N_EDGESC 1048576
#define HIDC 128
#define NUM_GRAPHSC 512
#define NUM_CLASSESC 10
#define NUM_EXPERTSC 4
#define NUM_LAYERSC 3

static const size_t NH = (size_t)N_NODESC * HIDC;

// ---------------- threefry2x32 (JAX-compatible, 20 rounds) ----------------
__host__ __device__ __forceinline__ uint32_t rotl32(uint32_t v, int r) {
  return (v << r) | (v >> (32 - r));
}
__host__ __device__ inline void threefry2x32(uint32_t k0, uint32_t k1,
                                             uint32_t x0, uint32_t x1,
                                             uint32_t* o0, uint32_t* o1) {
  uint32_t k2 = k0 ^ k1 ^ 0x1BD11BDAu;
  x0 += k0; x1 += k1;
#define TF_R(r) x0 += x1; x1 = rotl32(x1, r); x1 ^= x0;
  TF_R(13) TF_R(15) TF_R(26) TF_R(6)
  x0 += k1; x1 += k2 + 1u;
  TF_R(17) TF_R(29) TF_R(16) TF_R(24)
  x0 += k2; x1 += k0 + 2u;
  TF_R(13) TF_R(15) TF_R(26) TF_R(6)
  x0 += k0; x1 += k1 + 3u;
  TF_R(17) TF_R(29) TF_R(16) TF_R(24)
  x0 += k1; x1 += k2 + 4u;
  TF_R(13) TF_R(15) TF_R(26) TF_R(6)
  x0 += k2; x1 += k0 + 5u;
#undef TF_R
  *o0 = x0; *o1 = x1;
}

__device__ __forceinline__ float uniform_from_bits(uint32_t b) {
  float f = __uint_as_float((b >> 9) | 0x3f800000u) - 1.0f;
  const float mn = 1e-6f;
  const float mx = 1.0f - 1e-6f;
  return fmaxf(mn, __fadd_rn(__fmul_rn(f, __fsub_rn(mx, mn)), mn));
}

// ---------------- bf16 helpers ----------------
__device__ __forceinline__ float bf2f(unsigned short u) {
  return __uint_as_float(((uint32_t)u) << 16);
}
__device__ __forceinline__ unsigned short f2bf(float v) {
  uint32_t u = __float_as_uint(v);
  return (unsigned short)((u + 0x7FFFu + ((u >> 16) & 1u)) >> 16);
}

// ---------------- CSR build ----------------
__global__ void khist(const int* __restrict__ dst, int* __restrict__ deg) {
  int e = blockIdx.x * 256 + threadIdx.x;
  if (e < N_EDGESC) atomicAdd(&deg[dst[e]], 1);
}

__global__ void kscan(const int* __restrict__ deg, int* __restrict__ offs) {
  __shared__ int part[1024];
  int t = threadIdx.x;
  int base = t * 64;
  int s = 0;
  for (int i = 0; i < 64; ++i) s += deg[base + i];
  part[t] = s;
  __syncthreads();
  for (int off = 1; off < 1024; off <<= 1) {
    int v = 0;
    if (t >= off) v = part[t - off];
    __syncthreads();
    part[t] += v;
    __syncthreads();
  }
  int run = part[t] - s;
  for (int i = 0; i < 64; ++i) {
    int d = deg[base + i];
    offs[base + i] = run;
    run += d;
  }
  if (t == 1023) offs[N_NODESC] = run;
}

__global__ void kfill(const int* __restrict__ src, const int* __restrict__ dst,
                      int* __restrict__ curs, int* __restrict__ csr_src,
                      int* __restrict__ csr_eid) {
  int e = blockIdx.x * 256 + threadIdx.x;
  if (e >= N_EDGESC) return;
  int d = dst[e];
  int p = atomicAdd(&curs[d], 1);
  csr_src[p] = src[e];
  csr_eid[p] = e;
}

__global__ void ksort(const int* __restrict__ offs, int* __restrict__ csr_src,
                      int* __restrict__ csr_eid) {
  int n = blockIdx.x * 256 + threadIdx.x;
  if (n >= N_NODESC) return;
  int s = offs[n], e = offs[n + 1];
  for (int i = s + 1; i < e; ++i) {
    int ke = csr_eid[i], ks = csr_src[i];
    int j = i - 1;
    while (j >= s && csr_eid[j] > ke) {
      csr_eid[j + 1] = csr_eid[j];
      csr_src[j + 1] = csr_src[j];
      --j;
    }
    csr_eid[j + 1] = ke;
    csr_src[j + 1] = ks;
  }
}

__global__ void kbounds(const int* __restrict__ batch, int* __restrict__ bounds) {
  int g = threadIdx.x;
  int lo = 0, hi = N_NODESC;
  while (lo < hi) {
    int mid = (lo + hi) >> 1;
    if (batch[mid] < g) lo = mid + 1; else hi = mid;
  }
  bounds[g] = lo;
  if (g == 0) bounds[NUM_GRAPHSC] = N_NODESC;
}

// ---------------- f32 GIN gather (clean encoder; bit-exact path) -----------
__global__ void gather_z(const float* __restrict__ hin,
                         const int* __restrict__ offs,
                         const int* __restrict__ csr_src,
                         const float* __restrict__ epsArr, int l,
                         float* __restrict__ zout) {
  int gt = blockIdx.x * blockDim.x + threadIdx.x;
  int n = gt >> 6;
  int lane = gt & 63;
  if (n >= N_NODESC) return;
  int s = offs[n], e = offs[n + 1];
  float ax = 0.f, ay = 0.f;
  for (int i = s; i < e; ++i) {
    int sn = csr_src[i];
    const float2 v = *(const float2*)&hin[(size_t)sn * HIDC + lane * 2];
    ax = __fadd_rn(ax, v.x);
    ay = __fadd_rn(ay, v.y);
  }
  float ep = __fadd_rn(1.0f, epsArr[l]);
  const float2 hv = *(const float2*)&hin[(size_t)n * HIDC + lane * 2];
  ax = __fadd_rn(__fmul_rn(ep, hv.x), ax);
  ay = __fadd_rn(__fmul_rn(ep, hv.y), ay);
  float2 o; o.x = ax; o.y = ay;
  *(float2*)&zout[(size_t)n * HIDC + lane * 2] = o;
}

// ---------------- K-split GEMM body (f32 chain order preserved) ------------
// LDS: sX[k][m] 64x128 f32 (32KB) + sW[k][n] (32KB) -> 2 blocks/CU.
// XOR swizzle on the m/n byte offset: byte = m*4 ^ ((m&96)>>1).
// NOTE (round-5 bug): MXOR(m+4) != MXOR(m)+16 when (m&32) — the XOR mask bit 4
// interacts with the +16 carry. Always compute MXOR at the exact row.
__device__ __forceinline__ int MXOR(int m) { return (m * 4) ^ ((m & 96) >> 1); }

__device__ __forceinline__ void gemm_body(const float* __restrict__ Xf,
                                          const unsigned short* __restrict__ Xb,
                                          const float* __restrict__ W,
                                          const float* __restrict__ bias,
                                          float* __restrict__ Of,
                                          unsigned short* __restrict__ Ob,
                                          int doRelu, int tile) {
  __shared__ char sXb[64 * 512];
  __shared__ char sWb[64 * 512];
  const int tid = threadIdx.x;
  const size_t base = (size_t)tile * HIDC * HIDC;
  const int tm = (tid >> 4) << 3;
  const int tn = (tid & 15) << 3;
  const int xA = MXOR(tm), xA2 = MXOR(tm + 4);
  const int xB = MXOR(tn), xB2 = MXOR(tn + 4);

  float acc[8][8];
#pragma unroll
  for (int i = 0; i < 8; ++i)
#pragma unroll
    for (int j = 0; j < 8; ++j) acc[i][j] = 0.0f;

  for (int kh = 0; kh < 2; ++kh) {
    __syncthreads();
    if (Xb) {
      // bf16 input staging: 128 rows x 64 k half = 1024 x (8 bf16)
#pragma unroll
      for (int i = 0; i < 4; ++i) {
        int idx = tid + 256 * i;
        int m = idx >> 3;
        int kq = (idx & 7) * 8;
        const uint4 v = *(const uint4*)(Xb + base + (size_t)m * HIDC + kh * 64 + kq);
        uint32_t wds[4] = {v.x, v.y, v.z, v.w};
        int mo = MXOR(m);
#pragma unroll
        for (int c = 0; c < 4; ++c) {
          float f0 = __uint_as_float(wds[c] << 16);
          float f1 = __uint_as_float(wds[c] & 0xFFFF0000u);
          *(float*)(sXb + (kq + 2 * c + 0) * 512 + mo) = f0;
          *(float*)(sXb + (kq + 2 * c + 1) * 512 + mo) = f1;
        }
      }
    } else {
#pragma unroll
      for (int i = 0; i < 8; ++i) {
        int idx = tid + 256 * i;
        int m = idx >> 4;
        int kq = (idx & 15) * 4;
        float4 v = *(const float4*)(Xf + base + (size_t)m * HIDC + kh * 64 + kq);
        int mo = MXOR(m);
        *(float*)(sXb + (kq + 0) * 512 + mo) = v.x;
        *(float*)(sXb + (kq + 1) * 512 + mo) = v.y;
        *(float*)(sXb + (kq + 2) * 512 + mo) = v.z;
        *(float*)(sXb + (kq + 3) * 512 + mo) = v.w;
      }
    }
#pragma unroll
    for (int i = 0; i < 8; ++i) {
      int idx = tid + 256 * i;
      int kk = idx >> 5;
      int n0 = (idx & 31) * 4;
      float4 v = *(const float4*)(W + (size_t)(kh * 64 + kk) * HIDC + n0);
      *(float4*)(sWb + kk * 512 + MXOR(n0)) = v;
    }
    __syncthreads();

#pragma unroll 4
    for (int kk = 0; kk < 64; ++kk) {
      float4 a0 = *(const float4*)(sXb + kk * 512 + xA);
      float4 a1 = *(const float4*)(sXb + kk * 512 + xA2);
      float4 b0 = *(const float4*)(sWb + kk * 512 + xB);
      float4 b1 = *(const float4*)(sWb + kk * 512 + xB2);
      float a[8] = {a0.x, a0.y, a0.z, a0.w, a1.x, a1.y, a1.z, a1.w};
      float b[8] = {b0.x, b0.y, b0.z, b0.w, b1.x, b1.y, b1.z, b1.w};
#pragma unroll
      for (int i = 0; i < 8; ++i)
#pragma unroll
        for (int j = 0; j < 8; ++j) acc[i][j] = fmaf(a[i], b[j], acc[i][j]);
    }
  }

  float bvals[8];
#pragma unroll
  for (int j = 0; j < 8; ++j) bvals[j] = bias ? bias[tn + j] : 0.0f;
#pragma unroll
  for (int i = 0; i < 8; ++i) {
    float r[8];
#pragma unroll
    for (int j = 0; j < 8; ++j) {
      float v = __fadd_rn(acc[i][j], bvals[j]);
      if (doRelu) v = fmaxf(v, 0.0f);
      r[j] = v;
    }
    size_t off = base + (size_t)(tm + i) * HIDC + tn;
    if (Ob) {
      uint4 pk;
      pk.x = (uint32_t)f2bf(r[0]) | ((uint32_t)f2bf(r[1]) << 16);
      pk.y = (uint32_t)f2bf(r[2]) | ((uint32_t)f2bf(r[3]) << 16);
      pk.z = (uint32_t)f2bf(r[4]) | ((uint32_t)f2bf(r[5]) << 16);
      pk.w = (uint32_t)f2bf(r[6]) | ((uint32_t)f2bf(r[7]) << 16);
      *(uint4*)(Ob + off) = pk;
    } else {
      *(float4*)&Of[off] = *(float4*)&r[0];
      *(float4*)&Of[off + 4] = *(float4*)&r[4];
    }
  }
}

__global__ __launch_bounds__(256, 2)
void gemm_f32(const float* __restrict__ X, const float* __restrict__ W,
              const float* __restrict__ bias, float* __restrict__ O, int doRelu) {
  gemm_body(X, nullptr, W, bias, O, nullptr, doRelu, blockIdx.x);
}

// 4 mask-logit GEMMs of one expert in one dispatch (same X = Z)
__global__ __launch_bounds__(256, 2)
void gemm_f32x4(const float* __restrict__ X,
                const float* W0, const float* W1, const float* W2, const float* W3,
                const float* b0, const float* b1,
                float* o0, float* o1, float* o2, float* o3) {
  int slice = blockIdx.x >> 9;
  int tile = blockIdx.x & 511;
  const float* W; const float* bias; float* O; int relu;
  if (slice == 0)      { W = W0; bias = b0; O = o0; relu = 1; }
  else if (slice == 1) { W = W1; bias = b1; O = o1; relu = 1; }
  else if (slice == 2) { W = W2; bias = nullptr; O = o2; relu = 0; }
  else                 { W = W3; bias = nullptr; O = o3; relu = 0; }
  gemm_body(X, nullptr, W, bias, O, nullptr, relu, tile);
}

// batched bf16 GEMM across 4 experts (shared weights)
__global__ __launch_bounds__(256, 2)
void gemm_bf(const unsigned short* __restrict__ Xpool, const float* __restrict__ W,
             const float* __restrict__ bias, unsigned short* __restrict__ Opool,
             int doRelu) {
  int k = blockIdx.x >> 9;
  int tile = blockIdx.x & 511;
  gemm_body(nullptr, Xpool + (size_t)k * NH, W, bias, nullptr,
            Opool + (size_t)k * NH, doRelu, tile);
}

// ---------------- r[n] = dot(X[n,:], w) + b ----------------
__global__ void rowdot(const float* __restrict__ X, const float* __restrict__ w,
                       const float* __restrict__ bptr, float* __restrict__ r) {
  int gt = blockIdx.x * blockDim.x + threadIdx.x;
  int row = gt >> 6, lane = gt & 63;
  if (row >= N_NODESC) return;
  const float2 x = *(const float2*)&X[(size_t)row * HIDC + lane * 2];
  const float2 ww = *(const float2*)&w[lane * 2];
  float p = x.x * ww.x + x.y * ww.y;
#pragma unroll
  for (int m = 32; m; m >>= 1) p += __shfl_xor(p, m, 64);
  if (lane == 0) r[row] = p + bptr[0];
}

// ---------------- edge logits in CSR order (B-row register reuse) ----------
__global__ void edge_csrK(const float* __restrict__ A, const float* __restrict__ Bm,
                          const float* __restrict__ b1, const float* __restrict__ w2,
                          const float* __restrict__ b2,
                          const int* __restrict__ offs, const int* __restrict__ csr_src,
                          const int* __restrict__ csr_eid, float* __restrict__ el) {
  int n = blockIdx.x * 4 + (threadIdx.x >> 6);
  int lane = threadIdx.x & 63;
  const float2 b = *(const float2*)&Bm[(size_t)n * HIDC + lane * 2];
  const float2 bb = *(const float2*)&b1[lane * 2];
  const float2 w = *(const float2*)&w2[lane * 2];
  float bscalar = b2[0];
  int s = offs[n], e = offs[n + 1];
  for (int i = s; i < e; ++i) {
    int sn = csr_src[i];
    const float2 a = *(const float2*)&A[(size_t)sn * HIDC + lane * 2];
    float h0 = fmaxf(__fadd_rn(__fadd_rn(a.x, b.x), bb.x), 0.0f);
    float h1 = fmaxf(__fadd_rn(__fadd_rn(a.y, b.y), bb.y), 0.0f);
    float p = h0 * w.x + h1 * w.y;
#pragma unroll
    for (int m = 32; m; m >>= 1) p += __shfl_xor(p, m, 64);
    if (lane == 0) el[csr_eid[i]] = p + bscalar;
  }
}

// ---------------- hard-concrete sampling, f32-faithful decision -------------
__global__ void ksample(const float* __restrict__ lg, int n, uint32_t key0,
                        uint32_t key1, float* __restrict__ outp, int featMode) {
  int i = blockIdx.x * 256 + threadIdx.x;
  if (i >= n) return;
  uint32_t o0, o1;
  threefry2x32(key0, key1, 0u, (uint32_t)i, &o0, &o1);
  float u = uniform_from_bits(o0 ^ o1);
  float l = lg[i];
  float tf = -__logf(u);
  float gf = -__logf(tf);
  float margf = l + gf;
  float m;
  if (fabsf(margf) > 1e-4f) {
    m = (margf > 0.0f) ? 1.0f : 0.0f;
  } else {
    float t32 = (float)(-log((double)u));
    float g32 = (float)(-log((double)t32));
    float m32 = __fadd_rn(l, g32);
    float q = m32 / 0.1f;
    float e32 = (float)exp(-(double)q);
    float den = __fadd_rn(1.0f, e32);
    float s = 1.0f / den;
    m = (s > 0.5f) ? 1.0f : 0.0f;
  }
  if (featMode)
    outp[(size_t)(i >> 7) * (NUM_EXPERTSC * HIDC) + (i & 127)] = m;
  else
    outp[(size_t)i * NUM_EXPERTSC] = m;
}

// ---------------- masked_x (bf16), batched 4 experts ----------------
__global__ void kmaskxB(const float* __restrict__ x, const float* __restrict__ nmaskb,
                        const float* __restrict__ fmaskb,
                        unsigned short* __restrict__ hbpool) {
  int k = blockIdx.x >> 13;
  int t = (blockIdx.x & 8191) * 256 + threadIdx.x;  // 0..2M-1 (quad index)
  int n = t >> 5;
  int q = (t & 31) << 2;
  float nm = nmaskb[(size_t)n * NUM_EXPERTSC + k];
  float4 xv = *(const float4*)&x[(size_t)n * HIDC + q];
  float4 fv = *(const float4*)&fmaskb[(size_t)n * (NUM_EXPERTSC * HIDC) + k * HIDC + q];
  ushort2 p0, p1;
  p0.x = f2bf(xv.x * nm * fv.x); p0.y = f2bf(xv.y * nm * fv.y);
  p1.x = f2bf(xv.z * nm * fv.z); p1.y = f2bf(xv.w * nm * fv.w);
  uint2 pk; pk.x = (uint32_t)p0.x | ((uint32_t)p0.y << 16);
  pk.y = (uint32_t)p1.x | ((uint32_t)p1.y << 16);
  *(uint2*)(hbpool + (size_t)k * NH + (size_t)n * HIDC + q) = pk;
}

// ---------------- bf16 GIN gather, batched 4 experts ----------------
__global__ void gatherB(const unsigned short* __restrict__ hpool,
                        const int* __restrict__ offs, const int* __restrict__ csr_src,
                        const int* __restrict__ csr_eid,
                        const float* __restrict__ ewbase,  // out+OFF_EDGE, stride 4
                        const float* __restrict__ epsArr, int l,
                        unsigned short* __restrict__ aggpool) {
  int gid = blockIdx.x * 4 + (threadIdx.x >> 6);  // 0..262143
  int lane = threadIdx.x & 63;
  int k = gid >> 16;
  int n = gid & 65535;
  const unsigned short* h = hpool + (size_t)k * NH;
  const float* ew = ewbase + k;
  int s = offs[n], e = offs[n + 1];
  float ax = 0.f, ay = 0.f;
  for (int i = s; i < e; ++i) {
    int sn = csr_src[i];
    float w = ew[(size_t)csr_eid[i] * 4];
    uint32_t v = *(const uint32_t*)(h + (size_t)sn * HIDC + lane * 2);
    ax = fmaf(__uint_as_float(v << 16), w, ax);
    ay = fmaf(__uint_as_float(v & 0xFFFF0000u), w, ay);
  }
  float ep = 1.0f + epsArr[l];
  uint32_t hv = *(const uint32_t*)(h + (size_t)n * HIDC + lane * 2);
  ax = fmaf(ep, __uint_as_float(hv << 16), ax);
  ay = fmaf(ep, __uint_as_float(hv & 0xFFFF0000u), ay);
  uint32_t pk = (uint32_t)f2bf(ax) | ((uint32_t)f2bf(ay) << 16);
  *(uint32_t*)(aggpool + (size_t)k * NH + (size_t)n * HIDC + lane * 2) = pk;
}

// ---------------- mean pool (f32, clean Z) ----------------
__global__ void pool(const float* __restrict__ h, const int* __restrict__ bounds,
                     float* __restrict__ outp, int rowStride) {
  int g = blockIdx.x, j = threadIdx.x;
  int s = bounds[g], e = bounds[g + 1];
  float acc = 0.0f;
  for (int i = s; i < e; ++i) acc = __fadd_rn(acc, h[(size_t)i * HIDC + j]);
  int cnt = e - s; if (cnt < 1) cnt = 1;
  outp[(size_t)g * rowStride + j] = acc / (float)cnt;
}

// ---------------- mean pool (bf16 input), batched 4 experts ----------------
__global__ void poolB(const unsigned short* __restrict__ hbpool,
                      const int* __restrict__ bounds, float* __restrict__ outp) {
  int k = blockIdx.x >> 9;
  int g = blockIdx.x & 511;
  int j = threadIdx.x;
  const unsigned short* h = hbpool + (size_t)k * NH;
  int s = bounds[g], e = bounds[g + 1];
  float acc = 0.0f;
  for (int i = s; i < e; ++i) acc += bf2f(h[(size_t)i * HIDC + j]);
  int cnt = e - s; if (cnt < 1) cnt = 1;
  outp[(size_t)g * (NUM_EXPERTSC * HIDC) + k * HIDC + j] = acc / (float)cnt;
}

// ---------------- classifier, batched 4 experts ----------------
__global__ void kclsB(const float* __restrict__ hst, const float* __restrict__ w,
                      const float* __restrict__ b, float* __restrict__ outp) {
  int k = blockIdx.x >> 9;
  int g = blockIdx.x & 511;
  int c = threadIdx.x;
  if (c >= NUM_CLASSESC) return;
  float acc = 0.0f;
  for (int j = 0; j < HIDC; ++j)
    acc = __fadd_rn(acc, __fmul_rn(hst[(size_t)g * (NUM_EXPERTSC * HIDC) + k * HIDC + j],
                                   w[(size_t)k * HIDC * NUM_CLASSESC + j * NUM_CLASSESC + c]));
  outp[(size_t)g * (NUM_EXPERTSC * NUM_CLASSESC) + k * NUM_CLASSESC + c] =
      acc + b[k * NUM_CLASSESC + c];
}

// ---------------- launch ----------------
extern "C" void kernel_launch(void* const* d_in, const int* in_sizes, int n_in,
                              void* d_out, int out_size, void* d_ws, size_t ws_size,
                              hipStream_t stream) {
  const float* x    = (const float*)d_in[0];
  const int* eidx   = (const int*)d_in[1];
  const int* batch  = (const int*)d_in[2];
  const float* cw1  = (const float*)d_in[3];
  const float* cb1  = (const float*)d_in[4];
  const float* cw2  = (const float*)d_in[5];
  const float* cb2  = (const float*)d_in[6];
  const float* ceps = (const float*)d_in[7];
  const float* kw1  = (const float*)d_in[8];
  const float* kb1  = (const float*)d_in[9];
  const float* kw2  = (const float*)d_in[10];
  const float* kb2  = (const float*)d_in[11];
  const float* keps = (const float*)d_in[12];
  const float* nm_w1 = (const float*)d_in[13];
  const float* nm_b1 = (const float*)d_in[14];
  const float* nm_w2 = (const float*)d_in[15];
  const float* nm_b2 = (const float*)d_in[16];
  const float* em_w1 = (const float*)d_in[17];
  const float* em_b1 = (const float*)d_in[18];
  const float* em_w2 = (const float*)d_in[19];
  const float* em_b2 = (const float*)d_in[20];
  const float* fm_w1 = (const float*)d_in[21];
  const float* fm_b1 = (const float*)d_in[22];
  const float* fm_w2 = (const float*)d_in[23];
  const float* fm_b2 = (const float*)d_in[24];
  const float* cls_w = (const float*)d_in[25];
  const float* cls_b = (const float*)d_in[26];

  const int* src = eidx;
  const int* dstp = eidx + N_EDGESC;
  float* out = (float*)d_out;

  // output layout (floats)
  const size_t OFF_HST    = 20480;
  const size_t OFF_HORIG  = 282624;
  const size_t OFF_NODE   = 348160;
  const size_t OFF_EDGE   = 610304;
  const size_t OFF_FEAT   = 4804608;

  // workspace layout: pool of 6*NH f32, then el/nl/ints
  float* P  = (float*)d_ws;
  float* Zf = P;
  float* t1 = P + NH;
  float* t2 = P + 2 * NH;
  float* t3 = P + 3 * NH;
  float* t4 = P + 4 * NH;
  unsigned short* hbB  = (unsigned short*)P;             // phase 2 alias (4*NH u16)
  unsigned short* aggB = (unsigned short*)(P + 2 * NH);  // phase 2 alias
  unsigned short* tmpB = (unsigned short*)(P + 4 * NH);  // phase 2 alias
  float* el = P + 6 * NH;
  float* nl = el + N_EDGESC;
  int* deg    = (int*)(nl + N_NODESC);
  int* offs   = deg + N_NODESC;
  int* curs   = offs + N_NODESC + 1;
  int* csr_s  = curs + N_NODESC;
  int* csr_e  = csr_s + N_EDGESC;
  int* bounds = csr_e + N_EDGESC;

  // host-side key derivation (JAX threefry, partitionable-mode split)
  uint32_t kk[NUM_EXPERTSC][3][2];
  for (int k = 0; k < NUM_EXPERTSC; ++k) {
    uint32_t f0, f1;
    threefry2x32(0u, 42u, 0u, (uint32_t)k, &f0, &f1);
    threefry2x32(f0, f1, 0u, 0u, &kk[k][0][0], &kk[k][0][1]);
    threefry2x32(f0, f1, 0u, 1u, &kk[k][1][0], &kk[k][1][1]);
    threefry2x32(f0, f1, 0u, 2u, &kk[k][2][0], &kk[k][2][1]);
  }

  // ---- CSR build ----
  hipMemsetAsync(deg, 0, N_NODESC * sizeof(int), stream);
  khist<<<N_EDGESC / 256, 256, 0, stream>>>(dstp, deg);
  kscan<<<1, 1024, 0, stream>>>(deg, offs);
  hipMemcpyAsync(curs, offs, N_NODESC * sizeof(int), hipMemcpyDeviceToDevice, stream);
  kfill<<<N_EDGESC / 256, 256, 0, stream>>>(src, dstp, curs, csr_s, csr_e);
  ksort<<<N_NODESC / 256, 256, 0, stream>>>(offs, csr_s, csr_e);
  kbounds<<<1, NUM_GRAPHSC, 0, stream>>>(batch, bounds);

  const int GZ_GRID = N_NODESC * 64 / 256;   // 16384
  const int GEMM_GRID = N_NODESC / HIDC;     // 512

  // ---- clean encoder (f32, bit-exact) -> Zf ----
  for (int l = 0; l < NUM_LAYERSC; ++l) {
    const float* hin = (l == 0) ? x : t1;
    gather_z<<<GZ_GRID, 256, 0, stream>>>(hin, offs, csr_s, ceps, l, t3);
    gemm_f32<<<GEMM_GRID, 256, 0, stream>>>(t3, cw1 + (size_t)l * HIDC * HIDC,
                                            cb1 + l * HIDC, t2, 1);
    gemm_f32<<<GEMM_GRID, 256, 0, stream>>>(t2, cw2 + (size_t)l * HIDC * HIDC,
                                            cb2 + l * HIDC,
                                            (l == NUM_LAYERSC - 1) ? Zf : t1,
                                            (l < NUM_LAYERSC - 1) ? 1 : 0);
  }
  pool<<<NUM_GRAPHSC, HIDC, 0, stream>>>(Zf, bounds, out + OFF_HORIG, HIDC);

  // ---- phase 1: masks (f32 exact) ----
  for (int k = 0; k < NUM_EXPERTSC; ++k) {
    gemm_f32x4<<<4 * GEMM_GRID, 256, 0, stream>>>(
        Zf,
        nm_w1 + (size_t)k * HIDC * HIDC, fm_w1 + (size_t)k * HIDC * HIDC,
        em_w1 + (size_t)k * 2 * HIDC * HIDC,
        em_w1 + (size_t)k * 2 * HIDC * HIDC + HIDC * HIDC,
        nm_b1 + k * HIDC, fm_b1 + k * HIDC,
        t1, t2, t3, t4);
    // node mask
    rowdot<<<GZ_GRID, 256, 0, stream>>>(t1, nm_w2 + (size_t)k * HIDC, nm_b2 + k, nl);
    ksample<<<N_NODESC / 256, 256, 0, stream>>>(nl, N_NODESC, kk[k][0][0], kk[k][0][1],
                                                out + OFF_NODE + k, 0);
    // feature mask (fl reuses t1 after rowdot)
    gemm_f32<<<GEMM_GRID, 256, 0, stream>>>(t2, fm_w2 + (size_t)k * HIDC * HIDC,
                                            fm_b2 + (size_t)k * HIDC, t1, 0);
    ksample<<<(N_NODESC * HIDC) / 256, 256, 0, stream>>>(t1, N_NODESC * HIDC,
                                                         kk[k][2][0], kk[k][2][1],
                                                         out + OFF_FEAT + (size_t)k * HIDC, 1);
    // edge mask (CSR order, B-row reuse)
    edge_csrK<<<N_NODESC / 4, 256, 0, stream>>>(t3, t4, em_b1 + k * HIDC,
                                                em_w2 + (size_t)k * HIDC, em_b2 + k,
                                                offs, csr_s, csr_e, el);
    ksample<<<N_EDGESC / 256, 256, 0, stream>>>(el, N_EDGESC, kk[k][1][0], kk[k][1][1],
                                                out + OFF_EDGE + k, 0);
  }

  // ---- phase 2: masked encoders (bf16, batched across experts) ----
  kmaskxB<<<4 * 8192, 256, 0, stream>>>(x, out + OFF_NODE, out + OFF_FEAT, hbB);
  for (int l = 0; l < NUM_LAYERSC; ++l) {
    gatherB<<<4 * GZ_GRID, 256, 0, stream>>>(hbB, offs, csr_s, csr_e,
                                             out + OFF_EDGE, keps, l, aggB);
    gemm_bf<<<4 * GEMM_GRID, 256, 0, stream>>>(aggB, kw1 + (size_t)l * HIDC * HIDC,
                                               kb1 + l * HIDC, tmpB, 1);
    gemm_bf<<<4 * GEMM_GRID, 256, 0, stream>>>(tmpB, kw2 + (size_t)l * HIDC * HIDC,
                                               kb2 + l * HIDC, hbB,
                                               (l < NUM_LAYERSC - 1) ? 1 : 0);
  }
  poolB<<<4 * NUM_GRAPHSC, HIDC, 0, stream>>>(hbB, bounds, out + OFF_HST);
  kclsB<<<4 * NUM_GRAPHSC, 64, 0, stream>>>(out + OFF_HST, cls_w, cls_b, out);
}